// Round 1
// baseline (1723.444 us; speedup 1.0000x reference)
//
#include <hip/hip_runtime.h>

// HistLoss: per-channel histogram matching + MSE loss.
// C=64, H=W=512, HW=262144, NBINS=256, STRENGTH=100.
//
// Pipeline (all on `stream`):
//   0. memset bucket-hist (16MB) + small init kernel
//   1. k_count   : nI, nJ  (mask sums)
//   2. k_minmax  : per-channel masked min/max of J (uint-bit atomics, J>=0)
//   3. k_histJ   : per-channel 256-bin masked histogram of J (LDS hist)
//   4. k_cumsum  : hisF = cnt*(nI/nJ); cumJ = f32 sequential cumsum (matches ref rounding)
//   5. k_keyhist : 65536-bucket counting-sort histogram of masked I (key=(uint)(v*65536), exact)
//   6. k_scan    : per-channel exclusive scan of buckets (one block/channel)
//   7. k_scatter : masked I values into bucket-grouped storage (off[] becomes bucket ends)
//   8. k_loss    : per bucket: within-bucket rank (O(k^2), E[k]=2) -> global rank r ->
//                  searchsorted(cumJ, r, left) -> remap -> accumulate (v-val)^2 in double
//   9. k_final   : out = acc * 100 / (C*HW)
//
// ws usage: 16MB (off) + 64MB (values) + ~200KB smalls = ~81MB.

#define CN    64
#define HWN   262144
#define NB    256
#define NKEY  65536

__global__ void k_init(unsigned* __restrict__ hisCnt, unsigned* __restrict__ minb,
                       unsigned* __restrict__ maxb, unsigned* __restrict__ cnts,
                       double* __restrict__ lossacc){
  int i = blockIdx.x*256 + threadIdx.x;
  if(i < CN*NB) hisCnt[i] = 0u;
  if(i < CN){ minb[i] = 0x7F800000u; maxb[i] = 0u; }
  if(i == 0){ cnts[0] = 0u; cnts[1] = 0u; *lossacc = 0.0; }
}

__global__ void k_count(const int* __restrict__ mI, const int* __restrict__ mJ,
                        unsigned* __restrict__ cnts){
  __shared__ unsigned sI[256], sJ[256];
  int tid = threadIdx.x;
  unsigned a = 0, b = 0;
  for(int p = blockIdx.x*256 + tid; p < HWN; p += gridDim.x*256){
    a += (mI[p] > 0) ? 1u : 0u;
    b += (mJ[p] > 0) ? 1u : 0u;
  }
  sI[tid] = a; sJ[tid] = b; __syncthreads();
  for(int s = 128; s > 0; s >>= 1){
    if(tid < s){ sI[tid] += sI[tid+s]; sJ[tid] += sJ[tid+s]; }
    __syncthreads();
  }
  if(tid == 0){ atomicAdd(&cnts[0], sI[0]); atomicAdd(&cnts[1], sJ[0]); }
}

__global__ void k_minmax(const float* __restrict__ J, const int* __restrict__ mJ,
                         unsigned* __restrict__ minb, unsigned* __restrict__ maxb){
  int c = blockIdx.y;
  const float* Jc = J + (size_t)c * HWN;
  int tid = threadIdx.x;
  unsigned mn = 0x7F800000u, mx = 0u;
  for(int p = blockIdx.x*256 + tid; p < HWN; p += gridDim.x*256){
    if(mJ[p] > 0){
      unsigned u = __float_as_uint(Jc[p]);  // J in [0,1): nonneg -> bit order == value order
      mn = min(mn, u); mx = max(mx, u);
    }
  }
  __shared__ unsigned smn[256], smx[256];
  smn[tid] = mn; smx[tid] = mx; __syncthreads();
  for(int s = 128; s > 0; s >>= 1){
    if(tid < s){ smn[tid] = min(smn[tid], smn[tid+s]); smx[tid] = max(smx[tid], smx[tid+s]); }
    __syncthreads();
  }
  if(tid == 0){ atomicMin(&minb[c], smn[0]); atomicMax(&maxb[c], smx[0]); }
}

__global__ void k_histJ(const float* __restrict__ J, const int* __restrict__ mJ,
                        const unsigned* __restrict__ minb, const unsigned* __restrict__ maxb,
                        unsigned* __restrict__ hisCnt){
  int c = blockIdx.y;
  int tid = threadIdx.x;
  float mnv  = __uint_as_float(minb[c]);
  float mxv  = __uint_as_float(maxb[c]);
  float step = (mxv - mnv) / (float)NB;
  float den  = fmaxf(step, 1e-12f);
  __shared__ unsigned h[NB];
  h[tid] = 0u; __syncthreads();
  const float* Jc = J + (size_t)c * HWN;
  for(int p = blockIdx.x*256 + tid; p < HWN; p += gridDim.x*256){
    if(mJ[p] > 0){
      float bf = floorf((Jc[p] - mnv) / den);       // replicate ref: division, floor, clip
      bf = fminf(fmaxf(bf, 0.0f), 255.0f);
      atomicAdd(&h[(int)bf], 1u);
    }
  }
  __syncthreads();
  atomicAdd(&hisCnt[c*NB + tid], h[tid]);
}

__global__ void k_cumsum(const unsigned* __restrict__ hisCnt, const unsigned* __restrict__ cnts,
                         float* __restrict__ hisF, float* __restrict__ cumJ){
  int c = threadIdx.x;
  if(c >= CN) return;
  float ratio = (float)cnts[0] / (float)cnts[1];   // nI/nJ in f32, as in ref
  float cum = 0.0f;
  for(int b = 0; b < NB; b++){
    float h = (float)hisCnt[c*NB + b] * ratio;
    hisF[c*NB + b] = h;
    cum += h;                                       // sequential f32 cumsum == ref rounding
    cumJ[c*NB + b] = cum;
  }
}

__global__ void k_keyhist(const float* __restrict__ I, const int* __restrict__ mI,
                          unsigned* __restrict__ off){
  int c = blockIdx.y;
  const float* Ic = I + (size_t)c * HWN;
  unsigned* offc = off + (size_t)c * NKEY;
  for(int p = blockIdx.x*256 + threadIdx.x; p < HWN; p += gridDim.x*256){
    if(mI[p] > 0){
      float v = Ic[p];                              // v in [0,1)
      unsigned k = (unsigned)(v * 65536.0f);        // power-of-2 scale: exact, monotone
      if(k > 65535u) k = 65535u;
      atomicAdd(&offc[k], 1u);
    }
  }
}

__global__ void k_scan(unsigned* __restrict__ off){
  int c = blockIdx.x;
  unsigned* a = off + (size_t)c * NKEY;
  __shared__ unsigned s[256];
  int tid = threadIdx.x;
  unsigned carry = 0u;
  for(int t = 0; t < NKEY; t += 256){
    unsigned x = a[t + tid];
    s[tid] = x; __syncthreads();
    for(int d = 1; d < 256; d <<= 1){
      unsigned y = (tid >= d) ? s[tid - d] : 0u;
      __syncthreads();
      s[tid] += y;
      __syncthreads();
    }
    unsigned incl = s[tid];
    unsigned tot  = s[255];
    __syncthreads();
    a[t + tid] = carry + incl - x;                  // exclusive
    carry += tot;
  }
}

__global__ void k_scatter(const float* __restrict__ I, const int* __restrict__ mI,
                          unsigned* __restrict__ off, float* __restrict__ values){
  int c = blockIdx.y;
  const float* Ic = I + (size_t)c * HWN;
  unsigned* offc = off + (size_t)c * NKEY;
  float* valc = values + (size_t)c * HWN;
  for(int p = blockIdx.x*256 + threadIdx.x; p < HWN; p += gridDim.x*256){
    if(mI[p] > 0){
      float v = Ic[p];
      unsigned k = (unsigned)(v * 65536.0f);
      if(k > 65535u) k = 65535u;
      unsigned slot = atomicAdd(&offc[k], 1u);      // off[] becomes bucket END afterwards
      valc[slot] = v;
    }
  }
}

__global__ void k_loss(const float* __restrict__ values, const unsigned* __restrict__ off,
                       const float* __restrict__ hisF, const float* __restrict__ cumJ,
                       const unsigned* __restrict__ minb, const unsigned* __restrict__ maxb,
                       double* __restrict__ lossacc){
  int c = blockIdx.y;
  int tid = threadIdx.x;
  __shared__ float cs[NB], hs[NB];
  cs[tid] = cumJ[c*NB + tid];
  hs[tid] = hisF[c*NB + tid];
  __syncthreads();
  float mnv  = __uint_as_float(minb[c]);
  float step = (__uint_as_float(maxb[c]) - mnv) / (float)NB;
  int b = blockIdx.x*NB + tid;
  const unsigned* offc = off + (size_t)c * NKEY;
  const float* valc = values + (size_t)c * HWN;
  unsigned start = (b == 0) ? 0u : offc[b - 1];     // end of prev bucket == start of this one
  unsigned end   = offc[b];
  double acc = 0.0;
  for(unsigned i = start; i < end; i++){
    float vi = valc[i];
    unsigned wr = 0u;
    for(unsigned j = start; j < end; j++){          // within-bucket rank, E[k]=2
      if(j == i) continue;
      float vj = valc[j];
      if(vj < vi || (vj == vi && j < i)) wr++;
    }
    float rf = (float)(start + wr + 1u);            // global 1-indexed rank (exact in f32)
    // searchsorted(cumJ, rf, side='left')
    int lo = 0, hi = NB;
    while(lo < hi){
      int mid = (lo + hi) >> 1;
      if(cs[mid] < rf) lo = mid + 1; else hi = mid;
    }
    int bin = lo; if(bin > NB - 1) bin = NB - 1;
    float lov = cs[bin] - hs[bin];
    float ratio = (rf - lov) / fmaxf(hs[bin], 1e-12f);
    ratio = fminf(fmaxf(ratio, 0.0f), 1.0f);
    float val = mnv + ((float)bin + ratio) * step;
    float d = vi - val;
    acc += (double)d * (double)d;
  }
  __shared__ double sacc[NB];
  sacc[tid] = acc; __syncthreads();
  for(int s = 128; s > 0; s >>= 1){
    if(tid < s) sacc[tid] += sacc[tid+s];
    __syncthreads();
  }
  if(tid == 0) atomicAdd(lossacc, sacc[0]);
}

__global__ void k_final(const double* __restrict__ lossacc, float* __restrict__ out){
  out[0] = (float)(*lossacc * (100.0 / (double)((size_t)CN * HWN)));
}

extern "C" void kernel_launch(void* const* d_in, const int* in_sizes, int n_in,
                              void* d_out, int out_size, void* d_ws, size_t ws_size,
                              hipStream_t stream){
  const float* I  = (const float*)d_in[0];
  const float* J  = (const float*)d_in[1];
  const int*   mI = (const int*)d_in[2];
  const int*   mJ = (const int*)d_in[3];
  float* out = (float*)d_out;

  char* base = (char*)d_ws;
  size_t offB = (size_t)CN * NKEY * sizeof(unsigned);   // 16 MB
  size_t valB = (size_t)CN * HWN  * sizeof(float);      // 64 MB
  unsigned* off    = (unsigned*)base;
  float*    values = (float*)(base + offB);
  char* p = base + offB + valB;
  unsigned* hisCnt = (unsigned*)p; p += (size_t)CN*NB*sizeof(unsigned);
  float*    hisF   = (float*)p;    p += (size_t)CN*NB*sizeof(float);
  float*    cumJ   = (float*)p;    p += (size_t)CN*NB*sizeof(float);
  unsigned* minb   = (unsigned*)p; p += (size_t)CN*sizeof(unsigned);
  unsigned* maxb   = (unsigned*)p; p += (size_t)CN*sizeof(unsigned);
  unsigned* cnts   = (unsigned*)p; p += 2*sizeof(unsigned);
  double*   lossacc = (double*)p;  // 8-aligned: all prior sizes are multiples of 8

  hipMemsetAsync(off, 0, offB, stream);
  k_init<<<(CN*NB + 255)/256, 256, 0, stream>>>(hisCnt, minb, maxb, cnts, lossacc);
  k_count<<<256, 256, 0, stream>>>(mI, mJ, cnts);
  dim3 g(64, CN);
  k_minmax<<<g, 256, 0, stream>>>(J, mJ, minb, maxb);
  k_histJ<<<g, 256, 0, stream>>>(J, mJ, minb, maxb, hisCnt);
  k_cumsum<<<1, 64, 0, stream>>>(hisCnt, cnts, hisF, cumJ);
  k_keyhist<<<g, 256, 0, stream>>>(I, mI, off);
  k_scan<<<CN, 256, 0, stream>>>(off);
  k_scatter<<<g, 256, 0, stream>>>(I, mI, off, values);
  dim3 gl(NKEY/NB, CN);
  k_loss<<<gl, 256, 0, stream>>>(values, off, hisF, cumJ, minb, maxb, lossacc);
  k_final<<<1, 1, 0, stream>>>(lossacc, out);
}

// Round 2
// 1150.718 us; speedup vs baseline: 1.4977x; 1.4977x over previous
//
#include <hip/hip_runtime.h>

// HistLoss: per-channel histogram matching + MSE loss.
// C=64, H=W=512, HW=262144, NBINS=256, STRENGTH=100.
//
// R2 change: k_scatter + k_loss fused into k_rankloss. The 64MB bucket-grouped
// values array is gone (it only established within-bucket rank order; arrival
// order is equivalent to ~2e-9 in the loss, threshold 2.9e-6). Removes 541MB
// of random 4B-store write amplification seen in R1 rocprof.
//
// Pipeline:
//   0. memset off (16MB) + k_init smalls
//   1. k_count   : nI, nJ  (mask sums)
//   2. k_minmax  : per-channel masked min/max of J (uint-bit atomics, J>=0)
//   3. k_histJ   : per-channel 256-bin masked histogram of J (LDS hist)
//   4. k_cumsum  : hisF = cnt*(nI/nJ); cumJ = f32 sequential cumsum (ref rounding)
//   5. k_keyhist : 65536-bucket counting histogram of masked I (key=(uint)(v*65536))
//   6. k_scan    : per-channel exclusive scan of buckets (one block/channel)
//   7. k_rankloss: per masked pixel: slot=atomicAdd(off[k],1) -> rank=slot+1 ->
//                  searchsorted(cumJ,rank,left) -> remap -> (v-val)^2, double reduce
//   8. k_final   : out = acc * 100 / (C*HW)

#define CN    64
#define HWN   262144
#define NB    256
#define NKEY  65536

__global__ void k_init(unsigned* __restrict__ hisCnt, unsigned* __restrict__ minb,
                       unsigned* __restrict__ maxb, unsigned* __restrict__ cnts,
                       double* __restrict__ lossacc){
  int i = blockIdx.x*256 + threadIdx.x;
  if(i < CN*NB) hisCnt[i] = 0u;
  if(i < CN){ minb[i] = 0x7F800000u; maxb[i] = 0u; }
  if(i == 0){ cnts[0] = 0u; cnts[1] = 0u; *lossacc = 0.0; }
}

__global__ void k_count(const int* __restrict__ mI, const int* __restrict__ mJ,
                        unsigned* __restrict__ cnts){
  __shared__ unsigned sI[256], sJ[256];
  int tid = threadIdx.x;
  unsigned a = 0, b = 0;
  for(int p = blockIdx.x*256 + tid; p < HWN; p += gridDim.x*256){
    a += (mI[p] > 0) ? 1u : 0u;
    b += (mJ[p] > 0) ? 1u : 0u;
  }
  sI[tid] = a; sJ[tid] = b; __syncthreads();
  for(int s = 128; s > 0; s >>= 1){
    if(tid < s){ sI[tid] += sI[tid+s]; sJ[tid] += sJ[tid+s]; }
    __syncthreads();
  }
  if(tid == 0){ atomicAdd(&cnts[0], sI[0]); atomicAdd(&cnts[1], sJ[0]); }
}

__global__ void k_minmax(const float* __restrict__ J, const int* __restrict__ mJ,
                         unsigned* __restrict__ minb, unsigned* __restrict__ maxb){
  int c = blockIdx.y;
  const float* Jc = J + (size_t)c * HWN;
  int tid = threadIdx.x;
  unsigned mn = 0x7F800000u, mx = 0u;
  for(int p = blockIdx.x*256 + tid; p < HWN; p += gridDim.x*256){
    if(mJ[p] > 0){
      unsigned u = __float_as_uint(Jc[p]);  // J in [0,1): nonneg -> bit order == value order
      mn = min(mn, u); mx = max(mx, u);
    }
  }
  __shared__ unsigned smn[256], smx[256];
  smn[tid] = mn; smx[tid] = mx; __syncthreads();
  for(int s = 128; s > 0; s >>= 1){
    if(tid < s){ smn[tid] = min(smn[tid], smn[tid+s]); smx[tid] = max(smx[tid], smx[tid+s]); }
    __syncthreads();
  }
  if(tid == 0){ atomicMin(&minb[c], smn[0]); atomicMax(&maxb[c], smx[0]); }
}

__global__ void k_histJ(const float* __restrict__ J, const int* __restrict__ mJ,
                        const unsigned* __restrict__ minb, const unsigned* __restrict__ maxb,
                        unsigned* __restrict__ hisCnt){
  int c = blockIdx.y;
  int tid = threadIdx.x;
  float mnv  = __uint_as_float(minb[c]);
  float mxv  = __uint_as_float(maxb[c]);
  float step = (mxv - mnv) / (float)NB;
  float den  = fmaxf(step, 1e-12f);
  __shared__ unsigned h[NB];
  h[tid] = 0u; __syncthreads();
  const float* Jc = J + (size_t)c * HWN;
  for(int p = blockIdx.x*256 + tid; p < HWN; p += gridDim.x*256){
    if(mJ[p] > 0){
      float bf = floorf((Jc[p] - mnv) / den);       // replicate ref: division, floor, clip
      bf = fminf(fmaxf(bf, 0.0f), 255.0f);
      atomicAdd(&h[(int)bf], 1u);
    }
  }
  __syncthreads();
  atomicAdd(&hisCnt[c*NB + tid], h[tid]);
}

__global__ void k_cumsum(const unsigned* __restrict__ hisCnt, const unsigned* __restrict__ cnts,
                         float* __restrict__ hisF, float* __restrict__ cumJ){
  int c = threadIdx.x;
  if(c >= CN) return;
  float ratio = (float)cnts[0] / (float)cnts[1];   // nI/nJ in f32, as in ref
  float cum = 0.0f;
  for(int b = 0; b < NB; b++){
    float h = (float)hisCnt[c*NB + b] * ratio;
    hisF[c*NB + b] = h;
    cum += h;                                       // sequential f32 cumsum == ref rounding
    cumJ[c*NB + b] = cum;
  }
}

__global__ void k_keyhist(const float* __restrict__ I, const int* __restrict__ mI,
                          unsigned* __restrict__ off){
  int c = blockIdx.y;
  const float* Ic = I + (size_t)c * HWN;
  unsigned* offc = off + (size_t)c * NKEY;
  for(int p = blockIdx.x*256 + threadIdx.x; p < HWN; p += gridDim.x*256){
    if(mI[p] > 0){
      float v = Ic[p];                              // v in [0,1)
      unsigned k = (unsigned)(v * 65536.0f);        // power-of-2 scale: exact, monotone
      if(k > 65535u) k = 65535u;
      atomicAdd(&offc[k], 1u);
    }
  }
}

__global__ void k_scan(unsigned* __restrict__ off){
  int c = blockIdx.x;
  unsigned* a = off + (size_t)c * NKEY;
  __shared__ unsigned s[256];
  int tid = threadIdx.x;
  unsigned carry = 0u;
  for(int t = 0; t < NKEY; t += 256){
    unsigned x = a[t + tid];
    s[tid] = x; __syncthreads();
    for(int d = 1; d < 256; d <<= 1){
      unsigned y = (tid >= d) ? s[tid - d] : 0u;
      __syncthreads();
      s[tid] += y;
      __syncthreads();
    }
    unsigned incl = s[tid];
    unsigned tot  = s[255];
    __syncthreads();
    a[t + tid] = carry + incl - x;                  // exclusive
    carry += tot;
  }
}

// Fused scatter+loss: arrival order within a 1/65536 bucket stands in for exact
// value order (loss perturbation ~2e-9 << 2.9e-6 threshold). off[k] (exclusive
// start after k_scan) is used directly as the arrival counter: atomicAdd returns
// the pixel's 0-indexed global rank among masked pixels of its channel.
__global__ void k_rankloss(const float* __restrict__ I, const int* __restrict__ mI,
                           unsigned* __restrict__ off,
                           const float* __restrict__ hisF, const float* __restrict__ cumJ,
                           const unsigned* __restrict__ minb, const unsigned* __restrict__ maxb,
                           double* __restrict__ lossacc){
  int c = blockIdx.y;
  int tid = threadIdx.x;
  __shared__ float cs[NB], hs[NB];
  cs[tid] = cumJ[c*NB + tid];
  hs[tid] = hisF[c*NB + tid];
  __syncthreads();
  float mnv  = __uint_as_float(minb[c]);
  float step = (__uint_as_float(maxb[c]) - mnv) / (float)NB;
  const float* Ic = I + (size_t)c * HWN;
  unsigned* offc = off + (size_t)c * NKEY;
  double acc = 0.0;
  for(int p = blockIdx.x*256 + tid; p < HWN; p += gridDim.x*256){
    if(mI[p] > 0){
      float v = Ic[p];
      unsigned k = (unsigned)(v * 65536.0f);
      if(k > 65535u) k = 65535u;
      unsigned slot = atomicAdd(&offc[k], 1u);      // 0-indexed global rank
      float rf = (float)(slot + 1u);                // 1-indexed, exact in f32
      // searchsorted(cumJ, rf, side='left')
      int lo = 0, hi = NB;
      while(lo < hi){
        int mid = (lo + hi) >> 1;
        if(cs[mid] < rf) lo = mid + 1; else hi = mid;
      }
      int bin = lo; if(bin > NB - 1) bin = NB - 1;
      float lov = cs[bin] - hs[bin];
      float ratio = (rf - lov) / fmaxf(hs[bin], 1e-12f);
      ratio = fminf(fmaxf(ratio, 0.0f), 1.0f);
      float val = mnv + ((float)bin + ratio) * step;
      float d = v - val;
      acc += (double)d * (double)d;
    }
  }
  __shared__ double sacc[256];
  sacc[tid] = acc; __syncthreads();
  for(int s = 128; s > 0; s >>= 1){
    if(tid < s) sacc[tid] += sacc[tid+s];
    __syncthreads();
  }
  if(tid == 0) atomicAdd(lossacc, sacc[0]);
}

__global__ void k_final(const double* __restrict__ lossacc, float* __restrict__ out){
  out[0] = (float)(*lossacc * (100.0 / (double)((size_t)CN * HWN)));
}

extern "C" void kernel_launch(void* const* d_in, const int* in_sizes, int n_in,
                              void* d_out, int out_size, void* d_ws, size_t ws_size,
                              hipStream_t stream){
  const float* I  = (const float*)d_in[0];
  const float* J  = (const float*)d_in[1];
  const int*   mI = (const int*)d_in[2];
  const int*   mJ = (const int*)d_in[3];
  float* out = (float*)d_out;

  char* base = (char*)d_ws;
  size_t offB = (size_t)CN * NKEY * sizeof(unsigned);   // 16 MB
  unsigned* off    = (unsigned*)base;
  char* p = base + offB;
  unsigned* hisCnt = (unsigned*)p; p += (size_t)CN*NB*sizeof(unsigned);
  float*    hisF   = (float*)p;    p += (size_t)CN*NB*sizeof(float);
  float*    cumJ   = (float*)p;    p += (size_t)CN*NB*sizeof(float);
  unsigned* minb   = (unsigned*)p; p += (size_t)CN*sizeof(unsigned);
  unsigned* maxb   = (unsigned*)p; p += (size_t)CN*sizeof(unsigned);
  unsigned* cnts   = (unsigned*)p; p += 2*sizeof(unsigned);
  double*   lossacc = (double*)p;  // 8-aligned: all prior sizes are multiples of 8

  hipMemsetAsync(off, 0, offB, stream);
  k_init<<<(CN*NB + 255)/256, 256, 0, stream>>>(hisCnt, minb, maxb, cnts, lossacc);
  k_count<<<256, 256, 0, stream>>>(mI, mJ, cnts);
  dim3 g(64, CN);
  k_minmax<<<g, 256, 0, stream>>>(J, mJ, minb, maxb);
  k_histJ<<<g, 256, 0, stream>>>(J, mJ, minb, maxb, hisCnt);
  k_cumsum<<<1, 64, 0, stream>>>(hisCnt, cnts, hisF, cumJ);
  k_keyhist<<<g, 256, 0, stream>>>(I, mI, off);
  k_scan<<<CN, 256, 0, stream>>>(off);
  k_rankloss<<<g, 256, 0, stream>>>(I, mI, off, hisF, cumJ, minb, maxb, lossacc);
  k_final<<<1, 1, 0, stream>>>(lossacc, out);
}

// Round 3
// 269.315 us; speedup vs baseline: 6.3994x; 4.2728x over previous
//
#include <hip/hip_runtime.h>

// HistLoss: per-channel histogram matching + MSE loss.
// C=64, H=W=512, HW=262144, NBINS=256, STRENGTH=100.
//
// R3: eliminate ALL random global atomics (R2: 8.4M RMWs = 802MB beyond-L2
// traffic = ~665us). Key approximation: pair each masked pixel v with the
// MEAN remap value over its 1/8192-bucket's rank range instead of its exact
// rank's value. Error ~5e-8 in the loss (threshold 2.9e-6): the large smooth
// CDF-difference field cancels exactly; only within-bucket variance terms
// (~w^2/12 scale) remain. Then no per-pixel rank assignment exists at all:
//   loss = sum_c Q_c + sum_buckets [ -2*valbar'*S' + k*valbar'^2 ]
// where Q_c = sum (v-center)^2 (channel scalar), S' = sum (v-center) per
// bucket, valbar' = mean(val(rank)) - center over the bucket's rank range.
//
// Pipeline (7 dispatches, no memsets):
//   1. k_init   : zero hisCnt/minb/maxb/cnts/lossacc
//   2. k_minmax : per-channel masked min/max of J (float4) + nI/nJ counts (y==0)
//   3. k_histJ  : per-channel 256-bin masked histogram of J (float4, LDS hist)
//   4. k_cumsum : hisF = cnt*(nI/nJ); cumJ = f32 sequential cumsum (ref rounding)
//   5. k_bucket : per (c,blk): LDS {packed-u16 count, fixed-point sum(v-center)}
//                 over 8192 buckets -> coalesced partial writes; Q_c -> f64 atomic
//   6. k_closs  : per channel: combine partials in regs, scan counts (rank starts),
//                 walk cumJ incrementally, assemble loss terms in double
//   7. k_final  : out = acc * 100 / (C*HW)

#define CN    64
#define HWN   262144
#define NB    256
#define NBUK  8192
#define NBLK  4
#define BPIX  (HWN/NBLK)          // 65536 pixels per bucket-block
#define FXS   68719476736.0f      // 2^36 fixed-point scale for sum(v-center)
#define FXSI  (1.0/68719476736.0)

__global__ void k_init(unsigned* __restrict__ hisCnt, unsigned* __restrict__ minb,
                       unsigned* __restrict__ maxb, unsigned* __restrict__ cnts,
                       double* __restrict__ lossacc){
  int i = blockIdx.x*256 + threadIdx.x;
  if(i < CN*NB) hisCnt[i] = 0u;
  if(i < CN){ minb[i] = 0x7F800000u; maxb[i] = 0u; }
  if(i == 0){ cnts[0] = 0u; cnts[1] = 0u; *lossacc = 0.0; }
}

// masked min/max of J per channel (float4); blockIdx.y==0 also counts nI, nJ
// (masks are [1,1,H,W]: shared across channels, so one count suffices).
__global__ void k_minmax(const float* __restrict__ J, const int* __restrict__ mJ,
                         const int* __restrict__ mI,
                         unsigned* __restrict__ minb, unsigned* __restrict__ maxb,
                         unsigned* __restrict__ cnts){
  int c = blockIdx.y, tid = threadIdx.x;
  const float4* Jc = (const float4*)(J + (size_t)c * HWN);
  const int4*   Mj = (const int4*)mJ;
  const int4*   Mi = (const int4*)mI;
  bool docnt = (c == 0);
  unsigned mn = 0x7F800000u, mx = 0u, ci = 0, cj = 0;
  for(int p = blockIdx.x*256 + tid; p < HWN/4; p += 64*256){
    float4 v = Jc[p]; int4 m = Mj[p];
    if(m.x>0){unsigned u=__float_as_uint(v.x); mn=min(mn,u); mx=max(mx,u);}
    if(m.y>0){unsigned u=__float_as_uint(v.y); mn=min(mn,u); mx=max(mx,u);}
    if(m.z>0){unsigned u=__float_as_uint(v.z); mn=min(mn,u); mx=max(mx,u);}
    if(m.w>0){unsigned u=__float_as_uint(v.w); mn=min(mn,u); mx=max(mx,u);}
    if(docnt){
      int4 mi = Mi[p];
      cj += (m.x>0)+(m.y>0)+(m.z>0)+(m.w>0);
      ci += (mi.x>0)+(mi.y>0)+(mi.z>0)+(mi.w>0);
    }
  }
  __shared__ unsigned smn[256], smx[256], sci[256], scj[256];
  smn[tid]=mn; smx[tid]=mx; sci[tid]=ci; scj[tid]=cj; __syncthreads();
  for(int s = 128; s > 0; s >>= 1){
    if(tid < s){
      smn[tid]=min(smn[tid],smn[tid+s]); smx[tid]=max(smx[tid],smx[tid+s]);
      sci[tid]+=sci[tid+s]; scj[tid]+=scj[tid+s];
    }
    __syncthreads();
  }
  if(tid == 0){
    atomicMin(&minb[c], smn[0]); atomicMax(&maxb[c], smx[0]);
    if(docnt){ atomicAdd(&cnts[0], sci[0]); atomicAdd(&cnts[1], scj[0]); }
  }
}

__global__ void k_histJ(const float* __restrict__ J, const int* __restrict__ mJ,
                        const unsigned* __restrict__ minb, const unsigned* __restrict__ maxb,
                        unsigned* __restrict__ hisCnt){
  int c = blockIdx.y, tid = threadIdx.x;
  float mnv  = __uint_as_float(minb[c]);
  float mxv  = __uint_as_float(maxb[c]);
  float den  = fmaxf((mxv - mnv) / (float)NB, 1e-12f);
  __shared__ unsigned h[NB];
  h[tid] = 0u; __syncthreads();
  const float4* Jc = (const float4*)(J + (size_t)c * HWN);
  const int4*   Mj = (const int4*)mJ;
  for(int p = blockIdx.x*256 + tid; p < HWN/4; p += 64*256){
    float4 v = Jc[p]; int4 m = Mj[p];
    float vv[4] = {v.x,v.y,v.z,v.w};
    int   mm[4] = {m.x,m.y,m.z,m.w};
    #pragma unroll
    for(int e = 0; e < 4; e++){
      if(mm[e] > 0){
        float bf = floorf((vv[e] - mnv) / den);     // replicate ref: divide, floor, clip
        bf = fminf(fmaxf(bf, 0.0f), 255.0f);
        atomicAdd(&h[(int)bf], 1u);
      }
    }
  }
  __syncthreads();
  atomicAdd(&hisCnt[c*NB + tid], h[tid]);
}

__global__ void k_cumsum(const unsigned* __restrict__ hisCnt, const unsigned* __restrict__ cnts,
                         float* __restrict__ hisF, float* __restrict__ cumJ){
  int c = threadIdx.x;
  if(c >= CN) return;
  float ratio = (float)cnts[0] / (float)cnts[1];   // nI/nJ in f32, as in ref
  float cum = 0.0f;
  for(int b = 0; b < NB; b++){
    float h = (float)hisCnt[c*NB + b] * ratio;
    hisF[c*NB + b] = h;
    cum += h;                                       // sequential f32 cumsum == ref rounding
    cumJ[c*NB + b] = cum;
  }
}

// Per (channel, block-of-65536-pixels): LDS-aggregated bucket stats.
// cpk: packed ushort-pair counts (16KB). sfx: fixed-point sum(v-center) (32KB).
// Q_c (= sum (v-center)^2) accumulated per-thread and f64-atomic'd once/block.
__global__ __launch_bounds__(1024) void k_bucket(const float* __restrict__ I,
    const int* __restrict__ mI, unsigned* __restrict__ pc, int* __restrict__ ps,
    double* __restrict__ lossacc){
  int c = blockIdx.y, blk = blockIdx.x, tid = threadIdx.x;
  __shared__ unsigned cpk[NBUK/2];
  __shared__ int      sfx[NBUK];
  for(int i = tid; i < NBUK/2; i += 1024) cpk[i] = 0u;
  for(int i = tid; i < NBUK;   i += 1024) sfx[i] = 0;
  __syncthreads();
  const float4* Ic = (const float4*)(I + (size_t)c*HWN + (size_t)blk*BPIX);
  const int4*   Mc = (const int4*)(mI + (size_t)blk*BPIX);
  float q = 0.0f;
  for(int it = 0; it < BPIX/4096; ++it){            // 16 iters
    int idx = it*1024 + tid;
    float4 v4 = Ic[idx];
    int4   m4 = Mc[idx];
    float vv[4] = {v4.x,v4.y,v4.z,v4.w};
    int   mm[4] = {m4.x,m4.y,m4.z,m4.w};
    #pragma unroll
    for(int e = 0; e < 4; e++){
      if(mm[e] > 0){
        float v = vv[e];
        int k = (int)(v * (float)NBUK);             // power-of-2 scale: exact, monotone
        if(k > NBUK-1) k = NBUK-1;
        float dv = v - ((float)k + 0.5f) * (1.0f/(float)NBUK);  // exact center
        atomicAdd(&cpk[k>>1], 1u << ((k&1)*16));
        atomicAdd(&sfx[k], (int)rintf(dv * FXS));
        q += dv*dv;
      }
    }
  }
  __syncthreads();
  unsigned* pcb = pc + ((size_t)c*NBLK + blk)*(NBUK/2);
  int*      psb = ps + ((size_t)c*NBLK + blk)*NBUK;
  for(int i = tid; i < NBUK/2; i += 1024) pcb[i] = cpk[i];
  for(int i = tid; i < NBUK;   i += 1024) psb[i] = sfx[i];
  double qd = (double)q;
  for(int o = 32; o > 0; o >>= 1) qd += __shfl_down(qd, o, 64);
  __shared__ double sacc[16];
  int wid = tid >> 6, lane = tid & 63;
  if(lane == 0) sacc[wid] = qd;
  __syncthreads();
  if(tid == 0){
    double t = 0.0;
    for(int w = 0; w < 16; w++) t += sacc[w];
    atomicAdd(lossacc, t);
  }
}

// One block per channel. Thread t owns buckets [t*8, t*8+8): combines the 4
// block-partials in registers, scans counts for rank starts, then walks the
// 256-bin CDF incrementally (one binary search per thread, monotone advance).
__global__ __launch_bounds__(1024) void k_closs(const unsigned* __restrict__ pc,
    const int* __restrict__ ps, const float* __restrict__ hisF,
    const float* __restrict__ cumJ, const unsigned* __restrict__ minb,
    const unsigned* __restrict__ maxb, double* __restrict__ lossacc){
  int c = blockIdx.x, tid = threadIdx.x;
  __shared__ float cs[NB], hs[NB];
  __shared__ unsigned tsum[1024];
  __shared__ double red[1024];
  if(tid < NB){ cs[tid] = cumJ[c*NB + tid]; hs[tid] = hisF[c*NB + tid]; }

  unsigned kk[8] = {0,0,0,0,0,0,0,0};
  long long ss[8] = {0,0,0,0,0,0,0,0};
  for(int blk = 0; blk < NBLK; blk++){
    const unsigned* pcb = pc + ((size_t)c*NBLK + blk)*(NBUK/2) + tid*4;
    const int*      psb = ps + ((size_t)c*NBLK + blk)*NBUK + tid*8;
    #pragma unroll
    for(int jj = 0; jj < 4; jj++){
      unsigned w = pcb[jj];
      kk[2*jj]   += w & 0xFFFFu;
      kk[2*jj+1] += w >> 16;
    }
    #pragma unroll
    for(int j = 0; j < 8; j++) ss[j] += psb[j];
  }
  unsigned run = 0;
  unsigned loc[8];
  #pragma unroll
  for(int j = 0; j < 8; j++){ loc[j] = run; run += kk[j]; }
  tsum[tid] = run; __syncthreads();
  for(int d = 1; d < 1024; d <<= 1){                // Hillis-Steele inclusive scan
    unsigned x = (tid >= d) ? tsum[tid - d] : 0u;
    __syncthreads();
    tsum[tid] += x;
    __syncthreads();
  }
  unsigned texcl = (tid == 0) ? 0u : tsum[tid - 1];

  float mnv  = __uint_as_float(minb[c]);
  float step = (__uint_as_float(maxb[c]) - mnv) / (float)NB;
  // initial bin: searchsorted(cumJ, first rank, left), clipped
  float rf0 = (float)(texcl + 1u);
  int lo = 0, hi = NB;
  while(lo < hi){ int mid = (lo + hi) >> 1; if(cs[mid] < rf0) lo = mid + 1; else hi = mid; }
  int bin = (lo > NB-1) ? NB-1 : lo;

  double acc = 0.0;
  unsigned r = texcl;
  for(int j = 0; j < 8; j++){
    unsigned k = kk[j];
    if(k == 0) continue;
    double sval = 0.0;
    for(unsigned t2 = 0; t2 < k; t2++){
      r += 1u;
      float rf = (float)r;
      while(bin < NB-1 && cs[bin] < rf) bin++;      // monotone advance == left-search
      float lov = cs[bin] - hs[bin];
      float ratio = (rf - lov) / fmaxf(hs[bin], 1e-12f);
      ratio = fminf(fmaxf(ratio, 0.0f), 1.0f);
      float val = mnv + ((float)bin + ratio) * step; // f32, replicating ref per-rank math
      sval += (double)val;
    }
    double kb   = (double)k;
    double cb   = ((double)(tid*8 + j) + 0.5) * (1.0/(double)NBUK);
    double vbar = sval/kb - cb;                     // mean(val) - bucket center
    double S    = (double)ss[j] * FXSI;             // sum(v - center), de-fixed
    acc += kb*vbar*vbar - 2.0*vbar*S;
  }
  red[tid] = acc; __syncthreads();
  for(int s = 512; s > 0; s >>= 1){
    if(tid < s) red[tid] += red[tid + s];
    __syncthreads();
  }
  if(tid == 0) atomicAdd(lossacc, red[0]);
}

__global__ void k_final(const double* __restrict__ lossacc, float* __restrict__ out){
  out[0] = (float)(*lossacc * (100.0 / (double)((size_t)CN * HWN)));
}

extern "C" void kernel_launch(void* const* d_in, const int* in_sizes, int n_in,
                              void* d_out, int out_size, void* d_ws, size_t ws_size,
                              hipStream_t stream){
  const float* I  = (const float*)d_in[0];
  const float* J  = (const float*)d_in[1];
  const int*   mI = (const int*)d_in[2];
  const int*   mJ = (const int*)d_in[3];
  float* out = (float*)d_out;

  char* base = (char*)d_ws;
  size_t pcB = (size_t)CN * NBLK * (NBUK/2) * sizeof(unsigned);  // 4 MB packed counts
  size_t psB = (size_t)CN * NBLK * NBUK * sizeof(int);           // 8 MB fixed sums
  unsigned* pc = (unsigned*)base;
  int*      ps = (int*)(base + pcB);
  char* p = base + pcB + psB;
  unsigned* hisCnt = (unsigned*)p; p += (size_t)CN*NB*sizeof(unsigned);
  float*    hisF   = (float*)p;    p += (size_t)CN*NB*sizeof(float);
  float*    cumJ   = (float*)p;    p += (size_t)CN*NB*sizeof(float);
  unsigned* minb   = (unsigned*)p; p += (size_t)CN*sizeof(unsigned);
  unsigned* maxb   = (unsigned*)p; p += (size_t)CN*sizeof(unsigned);
  unsigned* cnts   = (unsigned*)p; p += 2*sizeof(unsigned);
  double*   lossacc = (double*)p;  // 8-aligned: all prior sizes are multiples of 8

  k_init<<<64, 256, 0, stream>>>(hisCnt, minb, maxb, cnts, lossacc);
  dim3 g(64, CN);
  k_minmax<<<g, 256, 0, stream>>>(J, mJ, mI, minb, maxb, cnts);
  k_histJ<<<g, 256, 0, stream>>>(J, mJ, minb, maxb, hisCnt);
  k_cumsum<<<1, 64, 0, stream>>>(hisCnt, cnts, hisF, cumJ);
  k_bucket<<<dim3(NBLK, CN), 1024, 0, stream>>>(I, mI, pc, ps, lossacc);
  k_closs<<<CN, 1024, 0, stream>>>(pc, ps, hisF, cumJ, minb, maxb, lossacc);
  k_final<<<1, 1, 0, stream>>>(lossacc, out);
}